// Round 15
// baseline (287.221 us; speedup 1.0000x reference)
//
#include <hip/hip_runtime.h>
#include <math.h>

// Fixed problem dims
constexpr int kB  = 4;
constexpr int kD  = 256;
constexpr int kNQ = 4096;
constexpr int kNK = 4096;
constexpr int kHW = 4096;   // 64*64

typedef __bf16 bf16x8 __attribute__((ext_vector_type(8)));
typedef float  f32x16 __attribute__((ext_vector_type(16)));

__device__ __forceinline__ unsigned short f2bf(float x) {
    unsigned int u = __builtin_bit_cast(unsigned int, x);
    u = (u + 0x7fffu + ((u >> 16) & 1u)) >> 16;
    return (unsigned short)u;
}

// =============================================== fused prep (1 launch, 15040 blocks)
__global__ __launch_bounds__(256) void k_prep(
    const float* __restrict__ v_in, const float* __restrict__ ow, ushort* __restrict__ v_bf,
    const float* __restrict__ qpos, ushort* __restrict__ qpos_bf,
    const float* __restrict__ kpos, ushort* __restrict__ kn_bf,
    const float* __restrict__ conv1_w, ushort* __restrict__ w9p,
    const float* __restrict__ w_vs, ushort* __restrict__ wvs_bf,
    const float* __restrict__ mlp_w2, ushort* __restrict__ w2_bf,
    const float* __restrict__ conv2_w, ushort* __restrict__ c2_bf,
    const float* __restrict__ mlp_w1, ushort* __restrict__ w1e_bf)
{
    const int bid = blockIdx.x, t = threadIdx.x;
    if (bid < 4096) {
        const int i = bid * 256 + t;
        float4 v = ((const float4*)v_in)[i];
        const float wsc = ow[i >> 6];
        ushort4 o;
        o.x = f2bf(v.x * wsc); o.y = f2bf(v.y * wsc);
        o.z = f2bf(v.z * wsc); o.w = f2bf(v.w * wsc);
        ((ushort4*)v_bf)[i] = o;
    } else if (bid < 8192) {
        const int i = (bid - 4096) * 256 + t;
        float4 v = ((const float4*)qpos)[i];
        ushort4 o;
        o.x = f2bf(v.x); o.y = f2bf(v.y); o.z = f2bf(v.z); o.w = f2bf(v.w);
        ((ushort4*)qpos_bf)[i] = o;
    } else if (bid < 12288) {
        const int row  = (bid - 8192) * 4 + (t >> 6);
        const int lane = t & 63;
        float4 v = ((const float4*)(kpos + (size_t)row * 256))[lane];
        float ss = v.x * v.x + v.y * v.y + v.z * v.z + v.w * v.w;
        #pragma unroll
        for (int off = 32; off; off >>= 1) ss += __shfl_xor(ss, off, 64);
        const float rn = 1.0f / sqrtf(ss);
        ushort4 o;
        o.x = f2bf(v.x * rn); o.y = f2bf(v.y * rn);
        o.z = f2bf(v.z * rn); o.w = f2bf(v.w * rn);
        ((ushort4*)(kn_bf + (size_t)row * 256))[lane] = o;
    } else if (bid < 14592) {
        const int idx = bid - 12288;
        const int s = idx >> 8, co = idx & 255, ci = t;
        const int oidx = ((s * 8 + (co >> 5)) * 16 + (ci >> 4)) * 512
                       + ((ci >> 3) & 1) * 256 + (co & 31) * 8 + (ci & 7);
        w9p[oidx] = f2bf(conv1_w[((size_t)co * 256 + ci) * 9 + s]);
    } else if (bid < 14784) {
        const float* src = (bid < 14656) ? w_vs : (bid < 14720) ? mlp_w2 : conv2_w;
        ushort* dst = (bid < 14656) ? wvs_bf : (bid < 14720) ? w2_bf : c2_bf;
        const int i = ((bid - 14592) & 63) * 256 + t;
        float4 v = ((const float4*)src)[i];
        ushort4 o;
        o.x = f2bf(v.x); o.y = f2bf(v.y); o.z = f2bf(v.z); o.w = f2bf(v.w);
        ((ushort4*)dst)[i] = o;
    } else {
        const int h = bid - 14784;
        w1e_bf[h * 256 + t] = f2bf(mlp_w1[h * 512 + t] + mlp_w1[h * 512 + 256 + t]);
    }
}

// ----------------------------------------------- staged MFMA GEMM  C = A @ W^T
// A [M,256] bf16, W [256,256] bf16 ([n][k]). Block: 128m x 128n, 8 waves (2m x 4n).
// EPI: 0 = f32 [m][256]; 1 = bf16 [m][256];
// EPI 2 = bf16 K-TILED transpose: [b][kt=m/32][n(256)][m%32] (16KB contiguous tiles)
template<int EPI, int RELU>
__global__ __launch_bounds__(512, 1) void k_gemm_mfma(
    const ushort* __restrict__ A, const ushort* __restrict__ W,
    const float* __restrict__ bias, void* __restrict__ outp)
{
    __shared__ __align__(16) char lds[131072];   // A 64K | W 64K (tr aliases A)
    const int t = threadIdx.x, w = t >> 6, l = t & 63, lr = l & 31, lh = l >> 5;
    const int wm = w >> 2, wn = w & 3;
    const int m0 = (blockIdx.x >> 1) * 128;
    const int n0 = (blockIdx.x & 1) * 128;
    const char* Ab = (const char*)A + (size_t)m0 * 512;
    const char* Wb = (const char*)W + (size_t)n0 * 512;
    #pragma unroll
    for (int i = 0; i < 8; ++i) {
        const int p = i * 512 + t;
        const int R = p >> 5, sl = p & 31;
        const int so = R * 512 + ((sl ^ (R & 31)) << 4);
        __builtin_amdgcn_global_load_lds(
            (const __attribute__((address_space(1))) unsigned*)(Ab + so),
            (__attribute__((address_space(3))) unsigned*)(lds + p * 16), 16, 0, 0);
        __builtin_amdgcn_global_load_lds(
            (const __attribute__((address_space(1))) unsigned*)(Wb + so),
            (__attribute__((address_space(3))) unsigned*)(lds + 65536 + p * 16), 16, 0, 0);
    }
    __syncthreads();
    const char* Abuf = lds;
    const char* Wbuf = lds + 65536;
    const int ar0 = wm * 64 + lr, ar1 = ar0 + 32;
    const int wrr = wn * 32 + lr;
    f32x16 c0{}, c1{};
    #pragma unroll
    for (int ks = 0; ks < 16; ++ks) {
        const int j = 2 * ks + lh;
        bf16x8 a0 = *(const bf16x8*)(Abuf + ar0 * 512 + ((j ^ lr) << 4));
        bf16x8 a1 = *(const bf16x8*)(Abuf + ar1 * 512 + ((j ^ lr) << 4));
        bf16x8 wf = *(const bf16x8*)(Wbuf + wrr * 512 + ((j ^ lr) << 4));
        c0 = __builtin_amdgcn_mfma_f32_32x32x16_bf16(a0, wf, c0, 0, 0, 0);
        c1 = __builtin_amdgcn_mfma_f32_32x32x16_bf16(a1, wf, c1, 0, 0, 0);
    }
    const int n = n0 + wn * 32 + lr;
    float bb = bias ? bias[n] : 0.f;
    if constexpr (EPI == 2) {
        __syncthreads();                         // all frag reads done before alias
        ushort (*tr)[136] = (ushort(*)[136])lds; // [n_local 128][m_local 128+pad]
        #pragma unroll
        for (int r = 0; r < 16; ++r) {
            const int ml = wm * 64 + (r & 3) + 8 * (r >> 2) + 4 * lh;
            float v0 = c0[r], v1 = c1[r];
            if (RELU) { v0 = fmaxf(v0, 0.f); v1 = fmaxf(v1, 0.f); }
            tr[wn * 32 + lr][ml]      = f2bf(v0);
            tr[wn * 32 + lr][ml + 32] = f2bf(v1);
        }
        __syncthreads();
        ushort* out = (ushort*)outp;
        const int b = m0 >> 12, mm = m0 & 4095;
        const int row = t >> 2, seg = t & 3;     // 128 rows x 4 segs of 32 m
        uint4 u0 = *(uint4*)&tr[row][seg * 32];
        uint4 u1 = *(uint4*)&tr[row][seg * 32 + 8];
        uint4 u2 = *(uint4*)&tr[row][seg * 32 + 16];
        uint4 u3 = *(uint4*)&tr[row][seg * 32 + 24];
        ushort* ob = out + ((size_t)(b * 128 + (mm >> 5) + seg) * 256 + n0 + row) * 32;
        *(uint4*)ob        = u0; *(uint4*)(ob + 8)  = u1;
        *(uint4*)(ob + 16) = u2; *(uint4*)(ob + 24) = u3;
    } else {
        #pragma unroll
        for (int r = 0; r < 16; ++r) {
            const int m = m0 + wm * 64 + (r & 3) + 8 * (r >> 2) + 4 * lh;
            float v0 = c0[r] + bb, v1 = c1[r] + bb;
            if (RELU) { v0 = fmaxf(v0, 0.f); v1 = fmaxf(v1, 0.f); }
            if constexpr (EPI == 0) {
                float* out = (float*)outp;
                out[(size_t)m * 256 + n]      = v0;
                out[(size_t)(m + 32) * 256 + n] = v1;
            } else {
                ushort* out = (ushort*)outp;
                out[(size_t)m * 256 + n]      = f2bf(v0);
                out[(size_t)(m + 32) * 256 + n] = f2bf(v1);
            }
        }
    }
}

// ---------------------------------------------------------------- MFMA attention
// Xpart[kseg][b][q][d] (bf16) = sum_{k in kseg} relu((q/|q|).kn) * vT'[d][k]
// k-split grid: 512 = b(4) x kseg(2) x qtile(64 rows). Block = 256 thr (4 waves):
// w0,w1 = QK producers (qg); w2,w3 = PV consumers (qg). 32k tiles, 72KB LDS ->
// 2 blocks/CU: independent barriers overlap (m114). Q-norm fused. No atomics.
__global__ __launch_bounds__(256, 2) void k_attn_mfma(
    const ushort* __restrict__ qbf, const ushort* __restrict__ kn,
    const ushort* __restrict__ vpT, ushort* __restrict__ Xp0,
    ushort* __restrict__ Xp1)
{
    __shared__ __align__(16) char lds[73728];   // K 2x16K @0 | V 2x16K @32768 | P 2x4K @65536
    const int t = threadIdx.x, w = t >> 6, l = t & 63, lr = l & 31, lh = l >> 5;
    const bool prod = (w < 2);
    const int qg = w & 1;
    const int bid0 = blockIdx.x;
    const int L = (bid0 & 7) * 64 + (bid0 >> 3);   // XCD clustering (512 = 8*64)
    const int b = L >> 7, kseg = (L >> 6) & 1, qt = L & 63;
    const int q0 = qt << 6;
    union U4 { unsigned u[4]; bf16x8 v; };

    // staging source offsets (pre-swizzled; dest is linear lane*16)
    int koff[4], voff[4];
    #pragma unroll
    for (int i = 0; i < 4; ++i) {
        const int p = i * 256 + t;
        {   // K tile [32 rows][512B], slot xor row
            const int R = p >> 5, sl = p & 31;
            koff[i] = R * 512 + ((sl ^ R) << 4);
        }
        {   // V tile [256d][32k] -> LDS [64 R][16 slots ^ (R&15)]
            const int R = p >> 4;
            const int slot = (p & 15) ^ (R & 15);
            voff[i] = R * 256 + (slot >> 2) * 64 + ((slot & 3) << 4);
        }
    }
    const char* kgb = (const char*)kn + ((size_t)b * 4096 + kseg * 2048) * 512;
    const char* vgb = (const char*)vpT + ((size_t)b * 128 + kseg * 64) * 16384;

    #define STAGE_K(bb, tc) do { \
        const char* ks_ = kgb + (size_t)(tc) * 16384; \
        char* kd_ = lds + (bb) * 16384; \
        _Pragma("unroll") \
        for (int i_ = 0; i_ < 4; ++i_) \
            __builtin_amdgcn_global_load_lds( \
                (const __attribute__((address_space(1))) unsigned*)(ks_ + koff[i_]), \
                (__attribute__((address_space(3))) unsigned*)(kd_ + (i_ * 256 + t) * 16), 16, 0, 0); \
        } while (0)
    #define STAGE_V(bb, tc) do { \
        const char* vs_ = vgb + (size_t)(tc) * 16384; \
        char* vd_ = lds + 32768 + (bb) * 16384; \
        _Pragma("unroll") \
        for (int i_ = 0; i_ < 4; ++i_) \
            __builtin_amdgcn_global_load_lds( \
                (const __attribute__((address_space(1))) unsigned*)(vs_ + voff[i_]), \
                (__attribute__((address_space(3))) unsigned*)(vd_ + (i_ * 256 + t) * 16), 16, 0, 0); \
        } while (0)

    // producers: load Q (bf16) + fused L2-norm (rn per q-row; q = lane&31 in S^T)
    bf16x8 qf[16];
    float rn = 0.f;
    if (prod) {
        const ushort* qrow = qbf + ((size_t)b * 4096 + q0 + qg * 32 + lr) * 256 + lh * 8;
        float ss = 0.f;
        #pragma unroll
        for (int ks = 0; ks < 16; ++ks) {
            bf16x8 qv = *(const bf16x8*)(qrow + ks * 16);
            qf[ks] = qv;
            U4 uu; uu.v = qv;
            #pragma unroll
            for (int wd = 0; wd < 4; ++wd) {
                float lo = __builtin_bit_cast(float, uu.u[wd] << 16);
                float hi = __builtin_bit_cast(float, uu.u[wd] & 0xffff0000u);
                ss += lo * lo + hi * hi;
            }
        }
        ss += __shfl_xor(ss, 32, 64);
        rn = rsqrtf(ss);
    }

    f32x16 o0{}, o1{}, o2{}, o3{}, o4{}, o5{}, o6{}, o7{};   // consumers: [32q][256d]

    STAGE_K(0, 0);
    __syncthreads();
    for (int tt = 0; tt <= 64; ++tt) {
        if (tt < 64) {
            if (tt + 1 < 64) STAGE_K((tt + 1) & 1, tt + 1);
            STAGE_V(tt & 1, tt);
        }
        if (!prod && tt > 0) {
            // load P(tt-1) SoA for this consumer's q-slice
            const unsigned* pr = (const unsigned*)(lds + 65536 + ((tt - 1) & 1) * 4096 + qg * 2048);
            U4 a0, a1;
            #pragma unroll
            for (int wd = 0; wd < 4; ++wd) {
                a0.u[wd] = pr[wd * 64 + l];
                a1.u[wd] = pr[(4 + wd) * 64 + l];
            }
            bf16x8 pf0 = a0.v, pf1 = a1.v;
            const char* vb = lds + 32768 + ((tt - 1) & 1) * 16384;
            #define PVD(OA, DB) { \
                const int R_ = (DB) * 8 + (lr >> 2); \
                const int s0_ = (lr & 3) * 4 + lh; \
                bf16x8 v0_ = *(const bf16x8*)(vb + R_ * 256 + (((s0_)     ^ (R_ & 15)) << 4)); \
                bf16x8 v1_ = *(const bf16x8*)(vb + R_ * 256 + (((s0_ + 2) ^ (R_ & 15)) << 4)); \
                OA = __builtin_amdgcn_mfma_f32_32x32x16_bf16(v0_, pf0, OA, 0, 0, 0); \
                OA = __builtin_amdgcn_mfma_f32_32x32x16_bf16(v1_, pf1, OA, 0, 0, 0); }
            PVD(o0, 0) PVD(o1, 1) PVD(o2, 2) PVD(o3, 3)
            PVD(o4, 4) PVD(o5, 5) PVD(o6, 6) PVD(o7, 7)
            #undef PVD
        }
        if (prod && tt < 64) {
            const char* kb = lds + (tt & 1) * 16384;
            f32x16 s0{}, s1{}, s2{}, s3{};
            #pragma unroll
            for (int ks = 0; ks < 16; ks += 4) {
                bf16x8 k0 = *(const bf16x8*)(kb + lr * 512 + (((2 * ks     + lh) ^ lr) << 4));
                bf16x8 k1 = *(const bf16x8*)(kb + lr * 512 + (((2 * ks + 2 + lh) ^ lr) << 4));
                bf16x8 k2 = *(const bf16x8*)(kb + lr * 512 + (((2 * ks + 4 + lh) ^ lr) << 4));
                bf16x8 k3 = *(const bf16x8*)(kb + lr * 512 + (((2 * ks + 6 + lh) ^ lr) << 4));
                s0 = __builtin_amdgcn_mfma_f32_32x32x16_bf16(k0, qf[ks],     s0, 0, 0, 0);
                s1 = __builtin_amdgcn_mfma_f32_32x32x16_bf16(k1, qf[ks + 1], s1, 0, 0, 0);
                s2 = __builtin_amdgcn_mfma_f32_32x32x16_bf16(k2, qf[ks + 2], s2, 0, 0, 0);
                s3 = __builtin_amdgcn_mfma_f32_32x32x16_bf16(k3, qf[ks + 3], s3, 0, 0, 0);
            }
            f32x16 s = (s0 + s1) + (s2 + s3);
            #define PKR(A, B) ((unsigned)f2bf(fmaxf((A), 0.f) * rn) | ((unsigned)f2bf(fmaxf((B), 0.f) * rn) << 16))
            unsigned p01 = PKR(s[0],  s[1]),  p23 = PKR(s[2],  s[3]);
            unsigned p45 = PKR(s[4],  s[5]),  p67 = PKR(s[6],  s[7]);
            unsigned p89 = PKR(s[8],  s[9]),  pAB = PKR(s[10], s[11]);
            unsigned pCD = PKR(s[12], s[13]), pEF = PKR(s[14], s[15]);
            #undef PKR
            unsigned e1a = lh ? p01 : p45,  e2a = lh ? p23 : p67;
            unsigned e1b = lh ? p89 : pCD,  e2b = lh ? pAB : pEF;
            unsigned f1a = (unsigned)__shfl_xor((int)e1a, 32, 64);
            unsigned f2a = (unsigned)__shfl_xor((int)e2a, 32, 64);
            unsigned f1b = (unsigned)__shfl_xor((int)e1b, 32, 64);
            unsigned f2b = (unsigned)__shfl_xor((int)e2b, 32, 64);
            U4 a0, a1;
            a0.u[0] = lh ? f1a : p01;  a0.u[1] = lh ? f2a : p23;
            a0.u[2] = lh ? p45 : f1a;  a0.u[3] = lh ? p67 : f2a;
            a1.u[0] = lh ? f1b : p89;  a1.u[1] = lh ? f2b : pAB;
            a1.u[2] = lh ? pCD : f1b;  a1.u[3] = lh ? pEF : f2b;
            unsigned* pw = (unsigned*)(lds + 65536 + (tt & 1) * 4096 + qg * 2048);
            #pragma unroll
            for (int wd = 0; wd < 4; ++wd) {
                pw[wd * 64 + l]       = a0.u[wd];
                pw[(4 + wd) * 64 + l] = a1.u[wd];
            }
        }
        if (tt < 64) __syncthreads();
    }
    #undef STAGE_K
    #undef STAGE_V
    // ---- epilogue: consumers store bf16 partials directly (r13-proven shape)
    if (!prod) {
        ushort* Xo = (kseg == 0 ? Xp0 : Xp1)
                   + ((size_t)b * 4096 + q0 + qg * 32 + lr) * 256;
        #define OUTD(OA, DB) _Pragma("unroll") \
            for (int r = 0; r < 16; r += 2) { \
                const int d_ = (DB) * 32 + (r & 3) + 8 * (r >> 2) + 4 * lh; \
                ushort2 u_; u_.x = f2bf((OA)[r]); u_.y = f2bf((OA)[r + 1]); \
                *(ushort2*)(Xo + d_) = u_; }
        OUTD(o0, 0) OUTD(o1, 1) OUTD(o2, 2) OUTD(o3, 3)
        OUTD(o4, 4) OUTD(o5, 5) OUTD(o6, 6) OUTD(o7, 7)
        #undef OUTD
    }
}

// ------------------------------ merge k-split partials: X = bf16(Xp0 + Xp1)
__global__ __launch_bounds__(256) void k_merge_x(const ushort* __restrict__ x0,
                                                const ushort* __restrict__ x1,
                                                ushort* __restrict__ xb) {
    const size_t i = ((size_t)blockIdx.x * 256 + threadIdx.x) * 8;
    uint4 a = *(const uint4*)(x0 + i);
    uint4 c = *(const uint4*)(x1 + i);
    uint4 o;
    const unsigned* ap = (const unsigned*)&a;
    const unsigned* cp = (const unsigned*)&c;
    unsigned* op = (unsigned*)&o;
    #pragma unroll
    for (int j = 0; j < 4; ++j) {
        float alo = __builtin_bit_cast(float, ap[j] << 16);
        float ahi = __builtin_bit_cast(float, ap[j] & 0xffff0000u);
        float clo = __builtin_bit_cast(float, cp[j] << 16);
        float chi = __builtin_bit_cast(float, cp[j] & 0xffff0000u);
        op[j] = (unsigned)f2bf(alo + clo) | ((unsigned)f2bf(ahi + chi) << 16);
    }
    *(uint4*)(xb + i) = o;
}

// ------------------------------- conv3x3 + BN + SiLU as 9 shifted MFMA GEMMs
__global__ __launch_bounds__(256, 2) void k_conv3_mfma(
    const ushort* __restrict__ X, const ushort* __restrict__ w9p,
    const float* __restrict__ bn_g, const float* __restrict__ bn_b,
    const float* __restrict__ bn_m, const float* __restrict__ bn_v,
    ushort* __restrict__ Y)
{
    __shared__ __align__(16) char smem[67584];   // 2x32KB bufs + 2KB bn (tr aliases bufs)
    float* bnv = (float*)(smem + 65536);
    const int t = threadIdx.x, w = t >> 6, l = t & 63, lr = l & 31, lh = l >> 5;
    {
        float inv = bn_g[t] * rsqrtf(bn_v[t] + 1e-3f);
        bnv[t]       = inv;
        bnv[256 + t] = bn_b[t] - bn_m[t] * inv;
    }
    const int bid = blockIdx.x;                  // 4b x 4ct x 32pt
    const int b = bid >> 7, ct = (bid >> 5) & 3, pt = bid & 31;
    const int co0 = ct * 64, p0 = pt * 128;
    const int wc = w >> 1, wp = w & 1;
    const int h0 = pt * 2 + wp;
    const int cb = ct * 2 + wc;
    const char* Xbytes = (const char*)(X + (size_t)b * 4096 * 256);
    const bf16x8 bz = {};
    f32x16 o0{}, o1{};

    #define CSTAGE(bufb, st_) do { \
        const char* src_ = Xbytes + (ptrdiff_t)(p0 + 64 * ((st_) >> 1) - 64) * 512 \
                         + ((st_) & 1) * 256; \
        char* dst_ = smem + (bufb) * 32768; \
        _Pragma("unroll") \
        for (int i_ = 0; i_ < 8; ++i_) { \
            const int di_ = i_ * 256 + t; \
            const int R_ = di_ >> 4, sl_ = di_ & 15; \
            __builtin_amdgcn_global_load_lds( \
                (const __attribute__((address_space(1))) unsigned*)(src_ + (ptrdiff_t)R_ * 512 + ((sl_ ^ (R_ & 15)) << 4)), \
                (__attribute__((address_space(3))) unsigned*)(dst_ + di_ * 16), 16, 0, 0); \
        } } while (0)

    CSTAGE(0, 0);
    __syncthreads();
    for (int st = 0; st < 6; ++st) {
        if (st < 5) CSTAGE((st + 1) & 1, st + 1);
        if (st < 5) asm volatile("s_waitcnt vmcnt(8)" ::: "memory");
        else        asm volatile("s_waitcnt vmcnt(0)" ::: "memory");
        __builtin_amdgcn_s_barrier();
        const char* xb = smem + (st & 1) * 32768;
        const int dyi = st >> 1, cih = st & 1;
        const int hh = h0 + dyi - 1;
        if (hh >= 0 && hh <= 63) {
            __builtin_amdgcn_s_setprio(1);
            #pragma unroll
            for (int dxi = 0; dxi < 3; ++dxi) {
                const int dx = dxi - 1;
                const int s = dyi * 3 + dxi;
                const bool mA = (dxi == 0) && (lr == 0);
                const bool mB = (dxi == 2) && (lr == 31);
                const int R0 = mA ? 0 : (wp * 64 + lr + dx);
                const int R1 = mB ? 0 : (wp * 64 + lr + dx + 32);
                const ushort* wb = w9p + ((size_t)(s * 8 + cb) * 16 + cih * 8) * 512 + l * 8;
                #pragma unroll
                for (int k8 = 0; k8 < 8; ++k8) {
                    bf16x8 af = *(const bf16x8*)(wb + k8 * 512);
                    bf16x8 b0 = *(const bf16x8*)(xb + R0 * 256 + (((k8 * 2 + lh) ^ (R0 & 15)) << 4));
                    bf16x8 b1 = *(const bf16x8*)(xb + R1 * 256 + (((k8 * 2 + lh) ^ (R1 & 15)) << 4));
                    if (mA) b0 = bz;
                    if (mB) b1 = bz;
                    o0 = __builtin_amdgcn_mfma_f32_32x32x16_bf16(af, b0, o0, 0, 0, 0);
                    o1 = __builtin_amdgcn_mfma_f32_32x32x16_bf16(af, b1, o1, 0, 0, 0);
                }
            }
            __builtin_amdgcn_s_setprio(0);
        }
        __builtin_amdgcn_s_barrier();
    }
    #undef CSTAGE
    ushort (*tr)[72] = (ushort(*)[72])smem;
    #pragma unroll
    for (int r = 0; r < 16; ++r) {
        const int co_l = wc * 32 + (r & 3) + 8 * (r >> 2) + 4 * lh;
        const int co = co0 + co_l;
        const float inv = bnv[co], add = bnv[256 + co];
        float x0 = o0[r] * inv + add;
        float x1 = o1[r] * inv + add;
        x0 = x0 / (1.f + expf(-x0));
        x1 = x1 / (1.f + expf(-x1));
        tr[wp * 64 + lr][co_l]      = f2bf(x0);
        tr[wp * 64 + 32 + lr][co_l] = f2bf(x1);
    }
    __syncthreads();
    const int pp = t >> 1, half = t & 1;
    uint4 u0 = *(uint4*)&tr[pp][half * 32];
    uint4 u1 = *(uint4*)&tr[pp][half * 32 + 8];
    uint4 u2 = *(uint4*)&tr[pp][half * 32 + 16];
    uint4 u3 = *(uint4*)&tr[pp][half * 32 + 24];
    ushort* yb = Y + ((size_t)b * 4096 + p0 + pp) * 256 + co0 + half * 32;
    *(uint4*)yb        = u0; *(uint4*)(yb + 8)  = u1;
    *(uint4*)(yb + 16) = u2; *(uint4*)(yb + 24) = u3;
}

// ------------------------- conv1x1 + bias + residual (LDS-staged GEMM form)
__global__ __launch_bounds__(512, 1) void k_conv1x1_mfma(
    const ushort* __restrict__ Y, const ushort* __restrict__ W2,
    const float* __restrict__ bias2, const float* __restrict__ query,
    float* __restrict__ out)
{
    __shared__ __align__(16) char lds[131072];   // Y 64K | W2 64K
    const int t = threadIdx.x, w = t >> 6, l = t & 63, lr = l & 31, lh = l >> 5;
    const int wc = w >> 2, wp = w & 3;
    const int bid = blockIdx.x;                  // b(4) x pt(32) x ct(2)
    const int b = bid >> 6, pt = (bid >> 1) & 31, ct = bid & 1;
    const int p0 = pt * 128, co0 = ct * 128;
    const char* Yb = (const char*)Y + ((size_t)b * 4096 + p0) * 512;
    const char* Wb = (const char*)W2 + (size_t)co0 * 512;
    #pragma unroll
    for (int i = 0; i < 8; ++i) {
        const int p = i * 512 + t;
        const int R = p >> 5, sl = p & 31;
        const int so = R * 512 + ((sl ^ (R & 31)) << 4);
        __builtin_amdgcn_global_load_lds(
            (const __attribute__((address_space(1))) unsigned*)(Yb + so),
            (__attribute__((address_space(3))) unsigned*)(lds + p * 16), 16, 0, 0);
        __builtin_amdgcn_global_load_lds(
            (const __attribute__((address_space(1))) unsigned*)(Wb + so),
            (__attribute__((address_space(3))) unsigned*)(lds + 65536 + p * 16), 16, 0, 0);
    }
    __syncthreads();
    const char* Ybuf = lds;
    const char* Wbuf = lds + 65536;
    const int cr0 = wc * 64 + lr, cr1 = cr0 + 32;
    const int yr  = wp * 32 + lr;
    f32x16 o0{}, o1{};
    #pragma unroll
    for (int ks = 0; ks < 16; ++ks) {
        const int j = 2 * ks + lh;
        bf16x8 w0 = *(const bf16x8*)(Wbuf + cr0 * 512 + ((j ^ lr) << 4));
        bf16x8 w1 = *(const bf16x8*)(Wbuf + cr1 * 512 + ((j ^ lr) << 4));
        bf16x8 yf = *(const bf16x8*)(Ybuf + yr  * 512 + ((j ^ lr) << 4));
        o0 = __builtin_amdgcn_mfma_f32_32x32x16_bf16(w0, yf, o0, 0, 0, 0);
        o1 = __builtin_amdgcn_mfma_f32_32x32x16_bf16(w1, yf, o1, 0, 0, 0);
    }
    const int p = p0 + wp * 32 + lr;
    #pragma unroll
    for (int r = 0; r < 16; ++r) {
        const int crow = (r & 3) + 8 * (r >> 2) + 4 * lh;
        const int coA = co0 + wc * 64 + crow;
        const int coB = coA + 32;
        const size_t baseA = ((size_t)b * 256 + coA) * 4096 + p;
        const size_t baseB = ((size_t)b * 256 + coB) * 4096 + p;
        out[baseA] = o0[r] + bias2[coA] + query[baseA];
        out[baseB] = o1[r] + bias2[coB] + query[baseB];
    }
}

// ---------------------------------------------------------------- launch
extern "C" void kernel_launch(void* const* d_in, const int* in_sizes, int n_in,
                              void* d_out, int out_size, void* d_ws, size_t ws_size,
                              hipStream_t stream) {
    const float* query   = (const float*)d_in[0];
    const float* v_in    = (const float*)d_in[1];
    const float* qpos    = (const float*)d_in[2];
    const float* kpos    = (const float*)d_in[3];
    const float* otherW  = (const float*)d_in[4];
    const float* w_vs    = (const float*)d_in[5];
    const float* mlp_w1  = (const float*)d_in[6];
    const float* mlp_b1  = (const float*)d_in[7];
    const float* mlp_w2  = (const float*)d_in[8];
    const float* mlp_b2  = (const float*)d_in[9];
    const float* conv1_w = (const float*)d_in[10];
    const float* bn_g    = (const float*)d_in[11];
    const float* bn_b    = (const float*)d_in[12];
    const float* bn_m    = (const float*)d_in[13];
    const float* bn_v    = (const float*)d_in[14];
    const float* conv2_w = (const float*)d_in[15];
    const float* conv2_b = (const float*)d_in[16];
    float* out = (float*)d_out;
    char* base = (char*)d_ws;

    constexpr size_t MB = 1u << 20;
    // [0,8):  v_bf (prep -> vproj) -> Xpart1 (attn out, v dead)
    // [8,16): qpos_bf (prep -> mlp1) -> qp_bf (mlp2 out -> attn) -> X_bf (merge out, qp dead)
    // [16,24): qhid_bf (mlp1 -> mlp2) -> Xpart0 (attn out, qhid dead) -> Y_bf (conv3 out)
    // [24,32): kn_bf ; [32,40): vT_bf ; [40,..): weights   (peak ~41.7MB)
    ushort* v_bf    = (ushort*)(base);
    ushort* Xpart1  = (ushort*)(base);
    ushort* qpos_bf = (ushort*)(base + 8 * MB);
    ushort* qp_bf   = (ushort*)(base + 8 * MB);
    ushort* X_bf    = (ushort*)(base + 8 * MB);
    ushort* qhid_bf = (ushort*)(base + 16 * MB);
    ushort* Xpart0  = (ushort*)(base + 16 * MB);
    ushort* Y_bf    = (ushort*)(base + 16 * MB);
    ushort* kn_bf   = (ushort*)(base + 24 * MB);
    ushort* vT_bf   = (ushort*)(base + 32 * MB);
    ushort* wvs_bf  = (ushort*)(base + 40 * MB);
    ushort* w1e_bf  = (ushort*)(base + 40 * MB + 128 * 1024);
    ushort* w2_bf   = (ushort*)(base + 40 * MB + 256 * 1024);
    ushort* c2_bf   = (ushort*)(base + 40 * MB + 384 * 1024);
    ushort* w9p_bf  = (ushort*)(base + 40 * MB + 512 * 1024);

    k_prep<<<15040, 256, 0, stream>>>(v_in, otherW, v_bf, qpos, qpos_bf,
                                      kpos, kn_bf, conv1_w, w9p_bf,
                                      w_vs, wvs_bf, mlp_w2, w2_bf,
                                      conv2_w, c2_bf, mlp_w1, w1e_bf);
    k_gemm_mfma<2, 0><<<256, 512, 0, stream>>>(v_bf, wvs_bf, nullptr, vT_bf);
    k_gemm_mfma<1, 1><<<256, 512, 0, stream>>>(qpos_bf, w1e_bf, mlp_b1, qhid_bf);
    k_gemm_mfma<1, 0><<<256, 512, 0, stream>>>(qhid_bf, w2_bf, mlp_b2, qp_bf);
    k_attn_mfma<<<512, 256, 0, stream>>>(qp_bf, kn_bf, vT_bf, Xpart0, Xpart1);
    k_merge_x<<<2048, 256, 0, stream>>>(Xpart0, Xpart1, X_bf);
    k_conv3_mfma<<<512, 256, 0, stream>>>(X_bf, w9p_bf, bn_g, bn_b, bn_m, bn_v, Y_bf);
    k_conv1x1_mfma<<<256, 512, 0, stream>>>(Y_bf, c2_bf, conv2_b, query, out);
}

// Round 17
// 180.884 us; speedup vs baseline: 1.5879x; 1.5879x over previous
//
#include <hip/hip_runtime.h>
#include <math.h>

// Fixed problem dims
constexpr int kB  = 4;
constexpr int kD  = 256;
constexpr int kNQ = 4096;
constexpr int kNK = 4096;
constexpr int kHW = 4096;   // 64*64

typedef __bf16 bf16x8 __attribute__((ext_vector_type(8)));
typedef float  f32x16 __attribute__((ext_vector_type(16)));

__device__ __forceinline__ unsigned short f2bf(float x) {
    unsigned int u = __builtin_bit_cast(unsigned int, x);
    u = (u + 0x7fffu + ((u >> 16) & 1u)) >> 16;
    return (unsigned short)u;
}

// =============================================== fused prep (1 launch, 15040 blocks)
__global__ __launch_bounds__(256) void k_prep(
    const float* __restrict__ v_in, const float* __restrict__ ow, ushort* __restrict__ v_bf,
    const float* __restrict__ qpos, ushort* __restrict__ qpos_bf,
    const float* __restrict__ kpos, ushort* __restrict__ kn_bf,
    const float* __restrict__ conv1_w, ushort* __restrict__ w9p,
    const float* __restrict__ w_vs, ushort* __restrict__ wvs_bf,
    const float* __restrict__ mlp_w2, ushort* __restrict__ w2_bf,
    const float* __restrict__ conv2_w, ushort* __restrict__ c2_bf,
    const float* __restrict__ mlp_w1, ushort* __restrict__ w1e_bf)
{
    const int bid = blockIdx.x, t = threadIdx.x;
    if (bid < 4096) {
        const int i = bid * 256 + t;
        float4 v = ((const float4*)v_in)[i];
        const float wsc = ow[i >> 6];
        ushort4 o;
        o.x = f2bf(v.x * wsc); o.y = f2bf(v.y * wsc);
        o.z = f2bf(v.z * wsc); o.w = f2bf(v.w * wsc);
        ((ushort4*)v_bf)[i] = o;
    } else if (bid < 8192) {
        const int i = (bid - 4096) * 256 + t;
        float4 v = ((const float4*)qpos)[i];
        ushort4 o;
        o.x = f2bf(v.x); o.y = f2bf(v.y); o.z = f2bf(v.z); o.w = f2bf(v.w);
        ((ushort4*)qpos_bf)[i] = o;
    } else if (bid < 12288) {
        const int row  = (bid - 8192) * 4 + (t >> 6);
        const int lane = t & 63;
        float4 v = ((const float4*)(kpos + (size_t)row * 256))[lane];
        float ss = v.x * v.x + v.y * v.y + v.z * v.z + v.w * v.w;
        #pragma unroll
        for (int off = 32; off; off >>= 1) ss += __shfl_xor(ss, off, 64);
        const float rn = 1.0f / sqrtf(ss);
        ushort4 o;
        o.x = f2bf(v.x * rn); o.y = f2bf(v.y * rn);
        o.z = f2bf(v.z * rn); o.w = f2bf(v.w * rn);
        ((ushort4*)(kn_bf + (size_t)row * 256))[lane] = o;
    } else if (bid < 14592) {
        const int idx = bid - 12288;
        const int s = idx >> 8, co = idx & 255, ci = t;
        const int oidx = ((s * 8 + (co >> 5)) * 16 + (ci >> 4)) * 512
                       + ((ci >> 3) & 1) * 256 + (co & 31) * 8 + (ci & 7);
        w9p[oidx] = f2bf(conv1_w[((size_t)co * 256 + ci) * 9 + s]);
    } else if (bid < 14784) {
        const float* src = (bid < 14656) ? w_vs : (bid < 14720) ? mlp_w2 : conv2_w;
        ushort* dst = (bid < 14656) ? wvs_bf : (bid < 14720) ? w2_bf : c2_bf;
        const int i = ((bid - 14592) & 63) * 256 + t;
        float4 v = ((const float4*)src)[i];
        ushort4 o;
        o.x = f2bf(v.x); o.y = f2bf(v.y); o.z = f2bf(v.z); o.w = f2bf(v.w);
        ((ushort4*)dst)[i] = o;
    } else {
        const int h = bid - 14784;
        w1e_bf[h * 256 + t] = f2bf(mlp_w1[h * 512 + t] + mlp_w1[h * 512 + 256 + t]);
    }
}

// ----------------------------------------------- staged MFMA GEMM  C = A @ W^T
// A [M,256] bf16, W [256,256] bf16 ([n][k]). Block: 128m x 128n, 8 waves (2m x 4n).
// EPI: 0 = f32 [m][256]; 1 = bf16 [m][256];
// EPI 2 = bf16 K-TILED transpose: [b][kt=m/32][n(256)][m%32] (16KB contiguous tiles)
template<int EPI, int RELU>
__global__ __launch_bounds__(512, 1) void k_gemm_mfma(
    const ushort* __restrict__ A, const ushort* __restrict__ W,
    const float* __restrict__ bias, void* __restrict__ outp)
{
    __shared__ __align__(16) char lds[131072];   // A 64K | W 64K (tr aliases A)
    const int t = threadIdx.x, w = t >> 6, l = t & 63, lr = l & 31, lh = l >> 5;
    const int wm = w >> 2, wn = w & 3;
    const int m0 = (blockIdx.x >> 1) * 128;
    const int n0 = (blockIdx.x & 1) * 128;
    const char* Ab = (const char*)A + (size_t)m0 * 512;
    const char* Wb = (const char*)W + (size_t)n0 * 512;
    #pragma unroll
    for (int i = 0; i < 8; ++i) {
        const int p = i * 512 + t;
        const int R = p >> 5, sl = p & 31;
        const int so = R * 512 + ((sl ^ (R & 31)) << 4);
        __builtin_amdgcn_global_load_lds(
            (const __attribute__((address_space(1))) unsigned*)(Ab + so),
            (__attribute__((address_space(3))) unsigned*)(lds + p * 16), 16, 0, 0);
        __builtin_amdgcn_global_load_lds(
            (const __attribute__((address_space(1))) unsigned*)(Wb + so),
            (__attribute__((address_space(3))) unsigned*)(lds + 65536 + p * 16), 16, 0, 0);
    }
    __syncthreads();
    const char* Abuf = lds;
    const char* Wbuf = lds + 65536;
    const int ar0 = wm * 64 + lr, ar1 = ar0 + 32;
    const int wrr = wn * 32 + lr;
    f32x16 c0{}, c1{};
    #pragma unroll
    for (int ks = 0; ks < 16; ++ks) {
        const int j = 2 * ks + lh;
        bf16x8 a0 = *(const bf16x8*)(Abuf + ar0 * 512 + ((j ^ lr) << 4));
        bf16x8 a1 = *(const bf16x8*)(Abuf + ar1 * 512 + ((j ^ lr) << 4));
        bf16x8 wf = *(const bf16x8*)(Wbuf + wrr * 512 + ((j ^ lr) << 4));
        c0 = __builtin_amdgcn_mfma_f32_32x32x16_bf16(a0, wf, c0, 0, 0, 0);
        c1 = __builtin_amdgcn_mfma_f32_32x32x16_bf16(a1, wf, c1, 0, 0, 0);
    }
    const int n = n0 + wn * 32 + lr;
    float bb = bias ? bias[n] : 0.f;
    if constexpr (EPI == 2) {
        __syncthreads();                         // all frag reads done before alias
        ushort (*tr)[136] = (ushort(*)[136])lds; // [n_local 128][m_local 128+pad]
        #pragma unroll
        for (int r = 0; r < 16; ++r) {
            const int ml = wm * 64 + (r & 3) + 8 * (r >> 2) + 4 * lh;
            float v0 = c0[r], v1 = c1[r];
            if (RELU) { v0 = fmaxf(v0, 0.f); v1 = fmaxf(v1, 0.f); }
            tr[wn * 32 + lr][ml]      = f2bf(v0);
            tr[wn * 32 + lr][ml + 32] = f2bf(v1);
        }
        __syncthreads();
        ushort* out = (ushort*)outp;
        const int b = m0 >> 12, mm = m0 & 4095;
        const int row = t >> 2, seg = t & 3;     // 128 rows x 4 segs of 32 m
        uint4 u0 = *(uint4*)&tr[row][seg * 32];
        uint4 u1 = *(uint4*)&tr[row][seg * 32 + 8];
        uint4 u2 = *(uint4*)&tr[row][seg * 32 + 16];
        uint4 u3 = *(uint4*)&tr[row][seg * 32 + 24];
        ushort* ob = out + ((size_t)(b * 128 + (mm >> 5) + seg) * 256 + n0 + row) * 32;
        *(uint4*)ob        = u0; *(uint4*)(ob + 8)  = u1;
        *(uint4*)(ob + 16) = u2; *(uint4*)(ob + 24) = u3;
    } else {
        #pragma unroll
        for (int r = 0; r < 16; ++r) {
            const int m = m0 + wm * 64 + (r & 3) + 8 * (r >> 2) + 4 * lh;
            float v0 = c0[r] + bb, v1 = c1[r] + bb;
            if (RELU) { v0 = fmaxf(v0, 0.f); v1 = fmaxf(v1, 0.f); }
            if constexpr (EPI == 0) {
                float* out = (float*)outp;
                out[(size_t)m * 256 + n]      = v0;
                out[(size_t)(m + 32) * 256 + n] = v1;
            } else {
                ushort* out = (ushort*)outp;
                out[(size_t)m * 256 + n]      = f2bf(v0);
                out[(size_t)(m + 32) * 256 + n] = f2bf(v1);
            }
        }
    }
}

// ---------------------------------------------------------------- MFMA attention
// X[b][q][d] (bf16) = sum_k relu((qp/|qp|).kn) * vT'[d][k]  (w folded in V')
// Q L2-norm fused; cross-tile pipelined QK dedup (r11); T5 setprio. r13-verified.
__global__ __launch_bounds__(512, 2) void k_attn_mfma(
    const float* __restrict__ qpf, const ushort* __restrict__ kn,
    const ushort* __restrict__ vpT, ushort* __restrict__ X)
{
    __shared__ __align__(16) char lds[147456];   // K 2x32K | V 2x32K | P 2x8K
    const int t = threadIdx.x, w = t >> 6, l = t & 63, lr = l & 31, lh = l >> 5;
    const int dh = w >> 2, qg = (w >> 1) & 1, kh = w & 1;
    const int bid0 = blockIdx.x;
    const int L = (bid0 & 7) * 32 + (bid0 >> 3);    // XCD clustering (256 = 8*32)
    const int b = L >> 6, qt = L & 63;
    const int q0 = qt << 6;
    union U4 { unsigned u[4]; bf16x8 v; };

    int koff[4], voff[4];
    #pragma unroll
    for (int i = 0; i < 4; ++i) {
        const int p = i * 512 + t;
        {
            const int R = p >> 5, sl = p & 31;
            koff[i] = R * 512 + ((sl ^ (R & 31)) << 4);
        }
        {
            const int sub = p >> 10, q = p & 1023;
            const int R = q >> 4, ch = (q & 15) ^ (R & 15);
            voff[i] = sub * 16384 + ((ch >> 2) * 64 + R) * 64 + ((ch & 3) << 4);
        }
    }
    const char* kgb = (const char*)(kn + (size_t)b * 4096 * 256);
    const char* vgb = (const char*)vpT + (size_t)b * 128 * 16384;

    #define STAGE_K(bb, tc) do { \
        const char* ks_ = kgb + (size_t)(tc) * 32768; \
        char* kd_ = lds + (bb) * 32768; \
        _Pragma("unroll") \
        for (int i_ = 0; i_ < 4; ++i_) \
            __builtin_amdgcn_global_load_lds( \
                (const __attribute__((address_space(1))) unsigned*)(ks_ + koff[i_]), \
                (__attribute__((address_space(3))) unsigned*)(kd_ + (i_ * 512 + w * 64) * 16), 16, 0, 0); \
        } while (0)
    #define STAGE_V(bb, tc) do { \
        const char* vs_ = vgb + (size_t)(tc) * 32768; \
        char* vd_ = lds + 65536 + (bb) * 32768; \
        _Pragma("unroll") \
        for (int i_ = 0; i_ < 4; ++i_) \
            __builtin_amdgcn_global_load_lds( \
                (const __attribute__((address_space(1))) unsigned*)(vs_ + voff[i_]), \
                (__attribute__((address_space(3))) unsigned*)(vd_ + (i_ * 512 + w * 64) * 16), 16, 0, 0); \
        } while (0)

    // Q load (dh=0 only): f32 -> bf16 frags + row sum-of-squares -> rn
    bf16x8 qf[16];
    float rn = 0.f;
    if (dh == 0) {
        const float* qrow = qpf + ((size_t)b * 4096 + q0 + qg * 32 + lr) * 256 + lh * 8;
        float ss = 0.f;
        #pragma unroll
        for (int ks = 0; ks < 16; ++ks) {
            float4 a = *(const float4*)(qrow + ks * 16);
            float4 c = *(const float4*)(qrow + ks * 16 + 4);
            ss += a.x * a.x + a.y * a.y + a.z * a.z + a.w * a.w
                + c.x * c.x + c.y * c.y + c.z * c.z + c.w * c.w;
            U4 q8a;
            q8a.u[0] = (unsigned)f2bf(a.x) | ((unsigned)f2bf(a.y) << 16);
            q8a.u[1] = (unsigned)f2bf(a.z) | ((unsigned)f2bf(a.w) << 16);
            q8a.u[2] = (unsigned)f2bf(c.x) | ((unsigned)f2bf(c.y) << 16);
            q8a.u[3] = (unsigned)f2bf(c.z) | ((unsigned)f2bf(c.w) << 16);
            qf[ks] = q8a.v;
        }
        ss += __shfl_xor(ss, 32, 64);
        rn = rsqrtf(ss);
    }

    f32x16 oa0{}, oa1{}, oa2{}, oa3{};
    bf16x8 pf0{}, pf1{};

    STAGE_K(0, 0);
    __syncthreads();
    for (int tt = 0; tt <= 64; ++tt) {
        if (tt < 64) {
            if (tt + 1 < 64) STAGE_K((tt + 1) & 1, tt + 1);
            STAGE_V(tt & 1, tt);
        }
        if (tt > 0) {
            const char* vb = lds + 65536 + ((tt - 1) & 1) * 32768 + kh * 16384;
            bf16x8 qp0, qp1;
            if (dh == 0) { qp0 = pf0; qp1 = pf1; }
            else {
                const unsigned* pr = (const unsigned*)(lds + 131072
                                   + ((tt - 1) & 1) * 8192 + (qg * 2 + kh) * 2048);
                U4 a0, a1;
                #pragma unroll
                for (int wd = 0; wd < 4; ++wd) {
                    a0.u[wd] = pr[wd * 64 + l];
                    a1.u[wd] = pr[(4 + wd) * 64 + l];
                }
                qp0 = a0.v; qp1 = a1.v;
            }
            __builtin_amdgcn_s_setprio(1);
            #define PVD(OA, DB) { \
                const int R_  = (((DB) & 1)) * 32 + lr; \
                const int sg_ = dh * 2 + ((DB) >> 1); \
                bf16x8 v0_ = *(const bf16x8*)(vb + R_ * 256 + ((((sg_ << 2) + lh)     ^ (lr & 15)) << 4)); \
                bf16x8 v1_ = *(const bf16x8*)(vb + R_ * 256 + ((((sg_ << 2) + 2 + lh) ^ (lr & 15)) << 4)); \
                OA = __builtin_amdgcn_mfma_f32_32x32x16_bf16(v0_, qp0, OA, 0, 0, 0); \
                OA = __builtin_amdgcn_mfma_f32_32x32x16_bf16(v1_, qp1, OA, 0, 0, 0); }
            PVD(oa0, 0) PVD(oa1, 1) PVD(oa2, 2) PVD(oa3, 3)
            #undef PVD
            __builtin_amdgcn_s_setprio(0);
        }
        if (dh == 0 && tt < 64) {
            const char* kb = lds + (tt & 1) * 32768 + kh * 16384;
            f32x16 s0{}, s1{}, s2{}, s3{};
            __builtin_amdgcn_s_setprio(1);
            #pragma unroll
            for (int ks = 0; ks < 16; ks += 4) {
                bf16x8 k0 = *(const bf16x8*)(kb + lr * 512 + (((2 * ks     + lh) ^ lr) << 4));
                bf16x8 k1 = *(const bf16x8*)(kb + lr * 512 + (((2 * ks + 2 + lh) ^ lr) << 4));
                bf16x8 k2 = *(const bf16x8*)(kb + lr * 512 + (((2 * ks + 4 + lh) ^ lr) << 4));
                bf16x8 k3 = *(const bf16x8*)(kb + lr * 512 + (((2 * ks + 6 + lh) ^ lr) << 4));
                s0 = __builtin_amdgcn_mfma_f32_32x32x16_bf16(k0, qf[ks],     s0, 0, 0, 0);
                s1 = __builtin_amdgcn_mfma_f32_32x32x16_bf16(k1, qf[ks + 1], s1, 0, 0, 0);
                s2 = __builtin_amdgcn_mfma_f32_32x32x16_bf16(k2, qf[ks + 2], s2, 0, 0, 0);
                s3 = __builtin_amdgcn_mfma_f32_32x32x16_bf16(k3, qf[ks + 3], s3, 0, 0, 0);
            }
            __builtin_amdgcn_s_setprio(0);
            f32x16 s = (s0 + s1) + (s2 + s3);
            #define PKR(A, B) ((unsigned)f2bf(fmaxf((A), 0.f) * rn) | ((unsigned)f2bf(fmaxf((B), 0.f) * rn) << 16))
            unsigned p01 = PKR(s[0],  s[1]),  p23 = PKR(s[2],  s[3]);
            unsigned p45 = PKR(s[4],  s[5]),  p67 = PKR(s[6],  s[7]);
            unsigned p89 = PKR(s[8],  s[9]),  pAB = PKR(s[10], s[11]);
            unsigned pCD = PKR(s[12], s[13]), pEF = PKR(s[14], s[15]);
            #undef PKR
            unsigned e1a = lh ? p01 : p45,  e2a = lh ? p23 : p67;
            unsigned e1b = lh ? p89 : pCD,  e2b = lh ? pAB : pEF;
            unsigned f1a = (unsigned)__shfl_xor((int)e1a, 32, 64);
            unsigned f2a = (unsigned)__shfl_xor((int)e2a, 32, 64);
            unsigned f1b = (unsigned)__shfl_xor((int)e1b, 32, 64);
            unsigned f2b = (unsigned)__shfl_xor((int)e2b, 32, 64);
            U4 a0, a1;
            a0.u[0] = lh ? f1a : p01;  a0.u[1] = lh ? f2a : p23;
            a0.u[2] = lh ? p45 : f1a;  a0.u[3] = lh ? p67 : f2a;
            a1.u[0] = lh ? f1b : p89;  a1.u[1] = lh ? f2b : pAB;
            a1.u[2] = lh ? pCD : f1b;  a1.u[3] = lh ? pEF : f2b;
            pf0 = a0.v; pf1 = a1.v;
            unsigned* pw = (unsigned*)(lds + 131072 + (tt & 1) * 8192 + (qg * 2 + kh) * 2048);
            #pragma unroll
            for (int wd = 0; wd < 4; ++wd) {
                pw[wd * 64 + l]       = a0.u[wd];
                pw[(4 + wd) * 64 + l] = a1.u[wd];
            }
        }
        if (tt < 64) __syncthreads();
    }
    #undef STAGE_K
    #undef STAGE_V
    float* red = (float*)lds;
    const int rowbase = ((qg * 2 + dh) * 32 + lr) * 132;
    if (kh == 1) {
        #define REDW(OA, DB) _Pragma("unroll") \
            for (int r = 0; r < 16; r += 2) { \
                const int d_ = (DB) * 32 + (r & 3) + 8 * (r >> 2) + 4 * lh; \
                *(float2*)&red[rowbase + d_] = make_float2((OA)[r], (OA)[r + 1]); }
        REDW(oa0, 0) REDW(oa1, 1) REDW(oa2, 2) REDW(oa3, 3)
        #undef REDW
    }
    __syncthreads();
    if (kh == 0) {
        ushort* Xb = X + ((size_t)b * 4096 + q0 + qg * 32 + lr) * 256 + dh * 128;
        #define OUTD(OA, DB) _Pragma("unroll") \
            for (int r = 0; r < 16; r += 2) { \
                const int d_ = (DB) * 32 + (r & 3) + 8 * (r >> 2) + 4 * lh; \
                float2 p = *(float2*)&red[rowbase + d_]; \
                ushort2 u_; u_.x = f2bf((OA)[r] + p.x); u_.y = f2bf((OA)[r + 1] + p.y); \
                *(ushort2*)(Xb + d_) = u_; }
        OUTD(oa0, 0) OUTD(oa1, 1) OUTD(oa2, 2) OUTD(oa3, 3)
        #undef OUTD
    }
}

// ------------------------------- conv3x3 + BN + SiLU as 9 shifted MFMA GEMMs
// Halo rows CLAMPED to [0,4095]: clamped rows only land in LDS slots that are
// masked (mA/mB) or guarded (hh), so results are identical and loads never OOB.
__global__ __launch_bounds__(256, 2) void k_conv3_mfma(
    const ushort* __restrict__ X, const ushort* __restrict__ w9p,
    const float* __restrict__ bn_g, const float* __restrict__ bn_b,
    const float* __restrict__ bn_m, const float* __restrict__ bn_v,
    ushort* __restrict__ Y)
{
    __shared__ __align__(16) char smem[67584];   // 2x32KB bufs + 2KB bn (tr aliases bufs)
    float* bnv = (float*)(smem + 65536);
    const int t = threadIdx.x, w = t >> 6, l = t & 63, lr = l & 31, lh = l >> 5;
    {
        float inv = bn_g[t] * rsqrtf(bn_v[t] + 1e-3f);
        bnv[t]       = inv;
        bnv[256 + t] = bn_b[t] - bn_m[t] * inv;
    }
    const int bid = blockIdx.x;                  // 4b x 4ct x 32pt
    const int b = bid >> 7, ct = (bid >> 5) & 3, pt = bid & 31;
    const int co0 = ct * 64, p0 = pt * 128;
    const int wc = w >> 1, wp = w & 1;
    const int h0 = pt * 2 + wp;
    const int cb = ct * 2 + wc;
    const char* Xbytes = (const char*)(X + (size_t)b * 4096 * 256);
    const bf16x8 bz = {};
    f32x16 o0{}, o1{};

    #define CSTAGE(bufb, st_) do { \
        const int rb_ = p0 + 64 * ((st_) >> 1) - 64; \
        const char* srcb_ = Xbytes + ((st_) & 1) * 256; \
        char* dst_ = smem + (bufb) * 32768; \
        _Pragma("unroll") \
        for (int i_ = 0; i_ < 8; ++i_) { \
            const int di_ = i_ * 256 + t; \
            const int R_ = di_ >> 4, sl_ = di_ & 15; \
            int Rg_ = rb_ + R_; \
            Rg_ = Rg_ < 0 ? 0 : (Rg_ > 4095 ? 4095 : Rg_); \
            __builtin_amdgcn_global_load_lds( \
                (const __attribute__((address_space(1))) unsigned*)(srcb_ + (ptrdiff_t)Rg_ * 512 + ((sl_ ^ (R_ & 15)) << 4)), \
                (__attribute__((address_space(3))) unsigned*)(dst_ + di_ * 16), 16, 0, 0); \
        } } while (0)

    CSTAGE(0, 0);
    __syncthreads();
    for (int st = 0; st < 6; ++st) {
        if (st < 5) CSTAGE((st + 1) & 1, st + 1);
        if (st < 5) asm volatile("s_waitcnt vmcnt(8)" ::: "memory");
        else        asm volatile("s_waitcnt vmcnt(0)" ::: "memory");
        __builtin_amdgcn_s_barrier();
        const char* xb = smem + (st & 1) * 32768;
        const int dyi = st >> 1, cih = st & 1;
        const int hh = h0 + dyi - 1;
        if (hh >= 0 && hh <= 63) {
            __builtin_amdgcn_s_setprio(1);
            #pragma unroll
            for (int dxi = 0; dxi < 3; ++dxi) {
                const int dx = dxi - 1;
                const int s = dyi * 3 + dxi;
                const bool mA = (dxi == 0) && (lr == 0);
                const bool mB = (dxi == 2) && (lr == 31);
                const int R0 = mA ? 0 : (wp * 64 + lr + dx);
                const int R1 = mB ? 0 : (wp * 64 + lr + dx + 32);
                const ushort* wb = w9p + ((size_t)(s * 8 + cb) * 16 + cih * 8) * 512 + l * 8;
                #pragma unroll
                for (int k8 = 0; k8 < 8; ++k8) {
                    bf16x8 af = *(const bf16x8*)(wb + k8 * 512);
                    bf16x8 b0 = *(const bf16x8*)(xb + R0 * 256 + (((k8 * 2 + lh) ^ (R0 & 15)) << 4));
                    bf16x8 b1 = *(const bf16x8*)(xb + R1 * 256 + (((k8 * 2 + lh) ^ (R1 & 15)) << 4));
                    if (mA) b0 = bz;
                    if (mB) b1 = bz;
                    o0 = __builtin_amdgcn_mfma_f32_32x32x16_bf16(af, b0, o0, 0, 0, 0);
                    o1 = __builtin_amdgcn_mfma_f32_32x32x16_bf16(af, b1, o1, 0, 0, 0);
                }
            }
            __builtin_amdgcn_s_setprio(0);
        }
        __builtin_amdgcn_s_barrier();
    }
    #undef CSTAGE
    ushort (*tr)[72] = (ushort(*)[72])smem;
    #pragma unroll
    for (int r = 0; r < 16; ++r) {
        const int co_l = wc * 32 + (r & 3) + 8 * (r >> 2) + 4 * lh;
        const int co = co0 + co_l;
        const float inv = bnv[co], add = bnv[256 + co];
        float x0 = o0[r] * inv + add;
        float x1 = o1[r] * inv + add;
        x0 = x0 / (1.f + expf(-x0));
        x1 = x1 / (1.f + expf(-x1));
        tr[wp * 64 + lr][co_l]      = f2bf(x0);
        tr[wp * 64 + 32 + lr][co_l] = f2bf(x1);
    }
    __syncthreads();
    const int pp = t >> 1, half = t & 1;
    uint4 u0 = *(uint4*)&tr[pp][half * 32];
    uint4 u1 = *(uint4*)&tr[pp][half * 32 + 8];
    uint4 u2 = *(uint4*)&tr[pp][half * 32 + 16];
    uint4 u3 = *(uint4*)&tr[pp][half * 32 + 24];
    ushort* yb = Y + ((size_t)b * 4096 + p0 + pp) * 256 + co0 + half * 32;
    *(uint4*)yb        = u0; *(uint4*)(yb + 8)  = u1;
    *(uint4*)(yb + 16) = u2; *(uint4*)(yb + 24) = u3;
}

// ------------------------- conv1x1 + bias + residual (LDS-staged GEMM form)
__global__ __launch_bounds__(512, 1) void k_conv1x1_mfma(
    const ushort* __restrict__ Y, const ushort* __restrict__ W2,
    const float* __restrict__ bias2, const float* __restrict__ query,
    float* __restrict__ out)
{
    __shared__ __align__(16) char lds[131072];   // Y 64K | W2 64K
    const int t = threadIdx.x, w = t >> 6, l = t & 63, lr = l & 31, lh = l >> 5;
    const int wc = w >> 2, wp = w & 3;
    const int bid = blockIdx.x;                  // b(4) x pt(32) x ct(2)
    const int b = bid >> 6, pt = (bid >> 1) & 31, ct = bid & 1;
    const int p0 = pt * 128, co0 = ct * 128;
    const char* Yb = (const char*)Y + ((size_t)b * 4096 + p0) * 512;
    const char* Wb = (const char*)W2 + (size_t)co0 * 512;
    #pragma unroll
    for (int i = 0; i < 8; ++i) {
        const int p = i * 512 + t;
        const int R = p >> 5, sl = p & 31;
        const int so = R * 512 + ((sl ^ (R & 31)) << 4);
        __builtin_amdgcn_global_load_lds(
            (const __attribute__((address_space(1))) unsigned*)(Yb + so),
            (__attribute__((address_space(3))) unsigned*)(lds + p * 16), 16, 0, 0);
        __builtin_amdgcn_global_load_lds(
            (const __attribute__((address_space(1))) unsigned*)(Wb + so),
            (__attribute__((address_space(3))) unsigned*)(lds + 65536 + p * 16), 16, 0, 0);
    }
    __syncthreads();
    const char* Ybuf = lds;
    const char* Wbuf = lds + 65536;
    const int cr0 = wc * 64 + lr, cr1 = cr0 + 32;
    const int yr  = wp * 32 + lr;
    f32x16 o0{}, o1{};
    #pragma unroll
    for (int ks = 0; ks < 16; ++ks) {
        const int j = 2 * ks + lh;
        bf16x8 w0 = *(const bf16x8*)(Wbuf + cr0 * 512 + ((j ^ lr) << 4));
        bf16x8 w1 = *(const bf16x8*)(Wbuf + cr1 * 512 + ((j ^ lr) << 4));
        bf16x8 yf = *(const bf16x8*)(Ybuf + yr  * 512 + ((j ^ lr) << 4));
        o0 = __builtin_amdgcn_mfma_f32_32x32x16_bf16(w0, yf, o0, 0, 0, 0);
        o1 = __builtin_amdgcn_mfma_f32_32x32x16_bf16(w1, yf, o1, 0, 0, 0);
    }
    const int p = p0 + wp * 32 + lr;
    #pragma unroll
    for (int r = 0; r < 16; ++r) {
        const int crow = (r & 3) + 8 * (r >> 2) + 4 * lh;
        const int coA = co0 + wc * 64 + crow;
        const int coB = coA + 32;
        const size_t baseA = ((size_t)b * 256 + coA) * 4096 + p;
        const size_t baseB = ((size_t)b * 256 + coB) * 4096 + p;
        out[baseA] = o0[r] + bias2[coA] + query[baseA];
        out[baseB] = o1[r] + bias2[coB] + query[baseB];
    }
}

// ---------------------------------------------------------------- launch
extern "C" void kernel_launch(void* const* d_in, const int* in_sizes, int n_in,
                              void* d_out, int out_size, void* d_ws, size_t ws_size,
                              hipStream_t stream) {
    const float* query   = (const float*)d_in[0];
    const float* v_in    = (const float*)d_in[1];
    const float* qpos    = (const float*)d_in[2];
    const float* kpos    = (const float*)d_in[3];
    const float* otherW  = (const float*)d_in[4];
    const float* w_vs    = (const float*)d_in[5];
    const float* mlp_w1  = (const float*)d_in[6];
    const float* mlp_b1  = (const float*)d_in[7];
    const float* mlp_w2  = (const float*)d_in[8];
    const float* mlp_b2  = (const float*)d_in[9];
    const float* conv1_w = (const float*)d_in[10];
    const float* bn_g    = (const float*)d_in[11];
    const float* bn_b    = (const float*)d_in[12];
    const float* bn_m    = (const float*)d_in[13];
    const float* bn_v    = (const float*)d_in[14];
    const float* conv2_w = (const float*)d_in[15];
    const float* conv2_b = (const float*)d_in[16];
    float* out = (float*)d_out;
    char* base = (char*)d_ws;

    constexpr size_t MB = 1u << 20;
    // r13-exact layout:
    // [0,16):  v_bf [0,8) + qpos_bf [8,16) (prep) -> qp_f32 (mlp2 out; both dead)
    // [16,24): qhid_bf (mlp1 out) -> X_bf (attn out; qhid dead)
    // [24,32): Y_bf (conv3 out)
    // [32,40): kn_bf ; [40,48): vT_bf ; [48,..): weights
    ushort* v_bf    = (ushort*)(base);
    ushort* qpos_bf = (ushort*)(base + 8 * MB);
    float*  qp_f32  = (float*) (base);
    ushort* qhid_bf = (ushort*)(base + 16 * MB);
    ushort* X_bf    = (ushort*)(base + 16 * MB);
    ushort* Y_bf    = (ushort*)(base + 24 * MB);
    ushort* kn_bf   = (ushort*)(base + 32 * MB);
    ushort* vT_bf   = (ushort*)(base + 40 * MB);
    ushort* wvs_bf  = (ushort*)(base + 48 * MB);
    ushort* w1e_bf  = (ushort*)(base + 48 * MB + 128 * 1024);
    ushort* w2_bf   = (ushort*)(base + 48 * MB + 256 * 1024);
    ushort* c2_bf   = (ushort*)(base + 48 * MB + 384 * 1024);
    ushort* w9p_bf  = (ushort*)(base + 48 * MB + 512 * 1024);

    k_prep<<<15040, 256, 0, stream>>>(v_in, otherW, v_bf, qpos, qpos_bf,
                                      kpos, kn_bf, conv1_w, w9p_bf,
                                      w_vs, wvs_bf, mlp_w2, w2_bf,
                                      conv2_w, c2_bf, mlp_w1, w1e_bf);
    k_gemm_mfma<2, 0><<<256, 512, 0, stream>>>(v_bf, wvs_bf, nullptr, vT_bf);
    k_gemm_mfma<1, 1><<<256, 512, 0, stream>>>(qpos_bf, w1e_bf, mlp_b1, qhid_bf);
    k_gemm_mfma<0, 0><<<256, 512, 0, stream>>>(qhid_bf, w2_bf, mlp_b2, qp_f32);
    k_attn_mfma<<<256, 512, 0, stream>>>(qp_f32, kn_bf, vT_bf, X_bf);
    k_conv3_mfma<<<512, 256, 0, stream>>>(X_bf, w9p_bf, bn_g, bn_b, bn_m, bn_v, Y_bf);
    k_conv1x1_mfma<<<256, 512, 0, stream>>>(Y_bf, c2_bf, conv2_b, query, out);
}